// Round 7
// baseline (209.035 us; speedup 1.0000x reference)
//
#include <hip/hip_runtime.h>
#include <hip/hip_bf16.h>
#include <math.h>

// TreeLSTM, B=8, L=4096, D=300, H=128, 12 levels. Round 7:
//  - level_ws: W-slice staged global->LDS once per block (40 KB GLDS), then
//    lane-private VGPR fragments via conflict-free ds_read_b128 (R6 loaded the
//    same 40 KB per-lane from global in EVERY wave = 160 KB/block VMEM).
//  - tail_kernel: levels 9-12 fused in ONE 512-thread block; A/c live in LDS
//    across levels, W in VGPRs, __syncthreads() between levels.
//  - leaf: double-buffered staging.
// Chunk-major layouts kept: unit u = [c=k/8][row] of 16B (8 bf16).

typedef __attribute__((ext_vector_type(8))) short bfrag8;   // 8 bf16 = 4 VGPRs
typedef __attribute__((ext_vector_type(4))) float f32x4;
typedef __attribute__((ext_vector_type(4))) short s16x4;

__device__ __forceinline__ float sigf(float x) { return 1.0f / (1.0f + __expf(-x)); }
__device__ __forceinline__ short f2bf(float f) {
    __hip_bfloat16 h = __float2bfloat16(f);
    return *reinterpret_cast<short*>(&h);
}
#define GLDS(gp, lp) __builtin_amdgcn_global_load_lds( \
    (const __attribute__((address_space(1))) void*)(gp), \
    (__attribute__((address_space(3))) void*)(lp), 16, 0, 0)

// ---------------- weight reorder (once, tiny) ----------------
__global__ __launch_bounds__(256) void reorder_kernel(
    const float* __restrict__ W_l, const float* __restrict__ W_r,
    const float* __restrict__ W_leaf,
    short* __restrict__ Wcat_ch, short* __restrict__ Wleaf_ch)
{
    int idx = blockIdx.x * 256 + threadIdx.x;
    if (idx < 163840) {
        int n = idx >> 8, k = idx & 255;
        float v = (k < 128) ? W_l[k * 640 + n] : W_r[(k - 128) * 640 + n];
        Wcat_ch[(((size_t)(k >> 3)) * 640 + n) * 8 + (k & 7)] = f2bf(v);
        return;
    }
    idx -= 163840;
    if (idx < 81920) {
        int n = idx / 320, k = idx - n * 320;
        short v = (k < 300) ? f2bf(W_leaf[k * 256 + n]) : (short)0;
        Wleaf_ch[(((size_t)(k >> 3)) * 256 + n) * 8 + (k & 7)] = v;
    }
}

// ---------------- x fp32 [32768][300] -> xbf chunk-major [40][32768] units ----------------
__global__ __launch_bounds__(256) void convx_kernel(
    const float* __restrict__ x, short* __restrict__ xbf)
{
    __shared__ short Ls[64 * 328];
    const int tid = threadIdx.x;
    const int R0 = blockIdx.x * 64;
    for (int i = tid; i < 64 * 75; i += 256) {
        int r = i / 75, q = i - r * 75;
        f32x4 v = *(const f32x4*)(x + (size_t)(R0 + r) * 300 + q * 4);
        s16x4 o;
        #pragma unroll
        for (int t = 0; t < 4; ++t) o[t] = f2bf(v[t]);
        *(s16x4*)(Ls + r * 328 + q * 4) = o;
    }
    for (int i = tid; i < 64 * 20; i += 256) {
        int r = i / 20, q = i - r * 20;
        Ls[r * 328 + 300 + q] = 0;
    }
    __syncthreads();
    for (int i = tid; i < 40 * 64; i += 256) {
        int c = i >> 6, r = i & 63;
        bfrag8 v = *(const bfrag8*)(Ls + r * 328 + c * 8);
        *(bfrag8*)(xbf + ((size_t)c * 32768 + R0 + r) * 8) = v;
    }
}

// ---------------- leaf: [32768,320]@[320,256] + bias, split h/c (double-buffered) ----------------
__global__ __launch_bounds__(256, 2) void leaf_kernel(
    const short* __restrict__ A, const short* __restrict__ B,
    const float* __restrict__ bleaf,
    short* __restrict__ hD,       // level-1 A, chunk layout [32][16384] units
    float* __restrict__ cD)       // [32768][128] fp32
{
    __shared__ short Als[2][8 * 128 * 8];   // 2 x 16 KB
    __shared__ short Bls[2][8 * 128 * 8];
    const int tid  = threadIdx.x;
    const int w    = tid >> 6, lane = tid & 63;
    const int quad = lane >> 4, l16 = lane & 15;
    const int mBlk = blockIdx.x * 128, nBlk = blockIdx.y * 128;
    const int waveM = (w >> 1) * 64, waveN = (w & 1) * 64;

    f32x4 acc[4][4] = {};

    auto stage = [&](int k0, int buf) {
        #pragma unroll
        for (int q = 0; q < 4; ++q) {
            int rr = w * 4 + q, cl = rr >> 1, rh = rr & 1;
            GLDS(A + ((size_t)(k0 + cl) * 32768 + mBlk + rh * 64 + lane) * 8,
                 (char*)Als[buf] + rr * 1024);
            GLDS(B + ((size_t)(k0 + cl) * 256 + nBlk + rh * 64 + lane) * 8,
                 (char*)Bls[buf] + rr * 1024);
        }
    };

    stage(0, 0);
    #pragma unroll
    for (int s = 0; s < 5; ++s) {
        __syncthreads();
        if (s < 4) stage((s + 1) * 8, (s + 1) & 1);
        const short* Ab = Als[s & 1];
        const short* Bb = Bls[s & 1];
        #pragma unroll
        for (int ks = 0; ks < 2; ++ks) {
            int ca = ks * 4 + quad;
            bfrag8 af[4], bf[4];
            #pragma unroll
            for (int i = 0; i < 4; ++i)
                af[i] = *(const bfrag8*)(Ab + (ca * 128 + waveM + i * 16 + l16) * 8);
            #pragma unroll
            for (int jn = 0; jn < 4; ++jn)
                bf[jn] = *(const bfrag8*)(Bb + (ca * 128 + waveN + jn * 16 + l16) * 8);
            #pragma unroll
            for (int i = 0; i < 4; ++i)
                #pragma unroll
                for (int jn = 0; jn < 4; ++jn)
                    acc[i][jn] = __builtin_amdgcn_mfma_f32_16x16x32_bf16(
                                     af[i], bf[jn], acc[i][jn], 0, 0, 0);
        }
    }

    #pragma unroll
    for (int i = 0; i < 4; ++i) {
        int row0 = mBlk + waveM + i * 16 + quad * 4;
        #pragma unroll
        for (int jn = 0; jn < 4; ++jn) {
            int col = nBlk + waveN + jn * 16 + l16;
            float bv = bleaf[col];
            #pragma unroll
            for (int rg = 0; rg < 4; ++rg) {
                float v = acc[i][jn][rg] + bv;
                int m = row0 + rg;
                if (nBlk == 0) {
                    int hc = col;
                    hD[(((size_t)((m & 1) * 16 + (hc >> 3))) * 16384 + (m >> 1)) * 8
                       + (hc & 7)] = f2bf(v);
                } else {
                    cD[(size_t)m * 128 + (col - 128)] = v;
                }
            }
        }
    }
}

// ---------------- weight-stationary level kernel (levels 1-8) ----------------
// grid (T, 8). Block (t,j): 64 rows x 16 h x 5 gates. W-slice: global -> LDS
// (40 KB, once) -> 160 VGPRs/lane. A tile 32 KB GLDS. Fused LSTM epilogue.
__global__ __launch_bounds__(256, 2) void level_ws_kernel(
    const short* __restrict__ A,      // [32][M] chunk units
    const float* __restrict__ cprev,  // [2M][128] fp32
    const short* __restrict__ Wch,    // [32][640] chunk units
    const float* __restrict__ bias,   // [640]
    short* __restrict__ hout, float* __restrict__ cout,
    int M, float* __restrict__ out_final)
{
    __shared__ short Wlds[32 * 80 * 8];   // 40 KB, layout [c][n'=g*16+hh]
    __shared__ short Als[32 * 64 * 8];    // 32 KB, layout [c][row]
    const int tid  = threadIdx.x;
    const int w    = tid >> 6, lane = tid & 63;
    const int quad = lane >> 4, l16 = lane & 15;
    const int j  = blockIdx.y;
    const int tb = blockIdx.x * 64;
    const int h  = j * 16 + l16;

    // ---- stage W slice: 40 rounds of 1KB (10/wave), per-lane global scatter ----
    #pragma unroll
    for (int q = 0; q < 10; ++q) {
        int r = w * 10 + q;
        int u = r * 64 + lane;              // flat unit in [c][80] layout
        int c = u / 80, np = u - c * 80;
        int g = np >> 4, hh = np & 15;
        GLDS(Wch + ((size_t)c * 640 + g * 128 + j * 16 + hh) * 8,
             (char*)Wlds + r * 1024);
    }
    // ---- stage A tile: 8 GLDS per wave ----
    {
        int row = tb + lane; if (row >= M) row = 0;
        #pragma unroll
        for (int s = 0; s < 8; ++s)
            GLDS(A + ((size_t)(s * 4 + w) * M + row) * 8,
                 (char*)Als + (s * 4 + w) * 1024);
    }
    __syncthreads();

    // ---- W fragments LDS -> VGPR (once; conflict-free: stride%8==0, l16-major) ----
    bfrag8 Wfr[5][8];
    #pragma unroll
    for (int g = 0; g < 5; ++g)
        #pragma unroll
        for (int s = 0; s < 8; ++s)
            Wfr[g][s] = *(const bfrag8*)(Wlds + (((s * 4 + quad) * 80) + g * 16 + l16) * 8);
    const float bi  = bias[h],       bfl = bias[128 + h], bfr_ = bias[256 + h];
    const float bo  = bias[384 + h], bg  = bias[512 + h];

    // ---- K-loop: 8 ksteps x (1 ds_read_b128 + 5 MFMA) ----
    f32x4 acc[5] = {};
    #pragma unroll
    for (int s = 0; s < 8; ++s) {
        bfrag8 af = *(const bfrag8*)(Als + ((s * 4 + quad) * 64 + w * 16 + l16) * 8);
        #pragma unroll
        for (int g = 0; g < 5; ++g)
            acc[g] = __builtin_amdgcn_mfma_f32_16x16x32_bf16(af, Wfr[g][s], acc[g], 0, 0, 0);
    }

    // ---- fused LSTM epilogue ----
    const int Mn = M >> 1;
    #pragma unroll
    for (int rg = 0; rg < 4; ++rg) {
        int m = tb + w * 16 + quad * 4 + rg;
        if (m < M) {
            float gi  = acc[0][rg] + bi;
            float gfl = acc[1][rg] + bfl;
            float gfr = acc[2][rg] + bfr_;
            float go  = acc[3][rg] + bo;
            float gg  = acc[4][rg] + bg;
            float cl  = cprev[(size_t)(2 * m) * 128 + h];
            float cr  = cprev[(size_t)(2 * m + 1) * 128 + h];
            float cn  = sigf(gfl) * cl + sigf(gfr) * cr + sigf(gi) * tanhf(gg);
            float hn  = sigf(go) * tanhf(cn);
            if (out_final) {
                out_final[(size_t)m * 128 + h] = hn;
            } else {
                hout[(((size_t)((m & 1) * 16 + (h >> 3))) * Mn + (m >> 1)) * 8
                     + (h & 7)] = f2bf(hn);
                cout[(size_t)m * 128 + h] = cn;
            }
        }
    }
}

// ---------------- tail: levels 9-12 (M=64,32,16,8) in ONE block ----------------
// 512 threads = 8 waves; wave = h-group j. W in VGPRs; A/c ping-pong in LDS.
__global__ __launch_bounds__(512, 2) void tail_kernel(
    const short* __restrict__ A9g,    // [32][64] units (h out of level 8)
    const float* __restrict__ c9in,   // [128][128] fp32 (c out of level 8)
    const short* __restrict__ Wch, const float* __restrict__ bias,
    float* __restrict__ out)
{
    __shared__ short A9[32 * 64 * 8];    // 32 KB
    __shared__ short A10[32 * 32 * 8];   // 16 KB
    __shared__ short A11[32 * 16 * 8];   //  8 KB
    __shared__ short A12[32 * 16 * 8];   //  8 KB (padded: only 8 rows used)
    __shared__ float c9[64 * 128];       // 32 KB
    __shared__ float c10[32 * 128];      // 16 KB
    __shared__ float c11[16 * 128];      //  8 KB
    const int tid  = threadIdx.x;
    const int w    = tid >> 6, lane = tid & 63;   // w = j
    const int quad = lane >> 4, l16 = lane & 15;
    const int h    = w * 16 + l16;

    // stage A9 from global: 32 rounds (4/wave)
    #pragma unroll
    for (int q = 0; q < 4; ++q) {
        int r = w * 4 + q;
        GLDS(A9g + ((size_t)r * 64 + lane) * 8, (char*)A9 + r * 1024);
    }
    // W fragments direct from global (one block: 320 KB once, overlaps GLDS)
    bfrag8 Wfr[5][8];
    #pragma unroll
    for (int g = 0; g < 5; ++g)
        #pragma unroll
        for (int s = 0; s < 8; ++s)
            Wfr[g][s] = *(const bfrag8*)(Wch + ((size_t)(s * 4 + quad) * 640
                                                + g * 128 + h) * 8);
    const float bi  = bias[h],       bfl = bias[128 + h], bfr_ = bias[256 + h];
    const float bo  = bias[384 + h], bg  = bias[512 + h];
    __syncthreads();

#define TAIL_LEVEL(MM, AINARR, CREAD, STORE)                                          \
    {                                                                                 \
        const int NT = ((MM) + 15) >> 4;                                              \
        for (int t0 = 0; t0 < NT; t0 += 2) {                                          \
            const int np = (NT - t0 < 2) ? (NT - t0) : 2;                             \
            f32x4 acc[2][5] = {};                                                     \
            for (int s = 0; s < 8; ++s) {                                             \
                for (int tt = 0; tt < np; ++tt) {                                     \
                    int rowl = (t0 + tt) * 16 + l16;                                  \
                    if (rowl >= (MM)) rowl = (MM) - 1;                                \
                    bfrag8 af = *(const bfrag8*)(AINARR                               \
                                  + ((s * 4 + quad) * (MM) + rowl) * 8);              \
                    for (int g = 0; g < 5; ++g)                                       \
                        acc[tt][g] = __builtin_amdgcn_mfma_f32_16x16x32_bf16(         \
                                         af, Wfr[g][s], acc[tt][g], 0, 0, 0);         \
                }                                                                     \
            }                                                                         \
            for (int tt = 0; tt < np; ++tt)                                           \
                for (int rg = 0; rg < 4; ++rg) {                                      \
                    int m = (t0 + tt) * 16 + quad * 4 + rg;                           \
                    if (m < (MM)) {                                                   \
                        float gi  = acc[tt][0][rg] + bi;                              \
                        float gfl = acc[tt][1][rg] + bfl;                             \
                        float gfr = acc[tt][2][rg] + bfr_;                            \
                        float go  = acc[tt][3][rg] + bo;                              \
                        float gg  = acc[tt][4][rg] + bg;                              \
                        float cl, cr; CREAD;                                          \
                        float cn = sigf(gfl) * cl + sigf(gfr) * cr                    \
                                 + sigf(gi) * tanhf(gg);                              \
                        float hn = sigf(go) * tanhf(cn);                              \
                        STORE;                                                        \
                    }                                                                 \
                }                                                                     \
        }                                                                             \
        __syncthreads();                                                              \
    }

    TAIL_LEVEL(64, A9,
        { cl = c9in[(size_t)(2 * m) * 128 + h]; cr = c9in[(size_t)(2 * m + 1) * 128 + h]; },
        { A10[(((m & 1) * 16 + (h >> 3)) * 32 + (m >> 1)) * 8 + (h & 7)] = f2bf(hn);
          c9[m * 128 + h] = cn; })
    TAIL_LEVEL(32, A10,
        { cl = c9[(2 * m) * 128 + h]; cr = c9[(2 * m + 1) * 128 + h]; },
        { A11[(((m & 1) * 16 + (h >> 3)) * 16 + (m >> 1)) * 8 + (h & 7)] = f2bf(hn);
          c10[m * 128 + h] = cn; })
    TAIL_LEVEL(16, A11,
        { cl = c10[(2 * m) * 128 + h]; cr = c10[(2 * m + 1) * 128 + h]; },
        { A12[(((m & 1) * 16 + (h >> 3)) * 8 + (m >> 1)) * 8 + (h & 7)] = f2bf(hn);
          c11[m * 128 + h] = cn; })
    TAIL_LEVEL(8, A12,
        { cl = c11[(2 * m) * 128 + h]; cr = c11[(2 * m + 1) * 128 + h]; },
        { out[(size_t)m * 128 + h] = hn; })
#undef TAIL_LEVEL
}

extern "C" void kernel_launch(void* const* d_in, const int* in_sizes, int n_in,
                              void* d_out, int out_size, void* d_ws, size_t ws_size,
                              hipStream_t stream)
{
    const float* x      = (const float*)d_in[0];
    const float* W_leaf = (const float*)d_in[1];
    const float* b_leaf = (const float*)d_in[2];
    const float* W_l    = (const float*)d_in[3];
    const float* W_r    = (const float*)d_in[4];
    const float* b      = (const float*)d_in[5];
    float* out = (float*)d_out;

    // workspace (~59 MB)
    char* p = (char*)d_ws;
    short* xbf   = (short*)p; p += (size_t)40 * 32768 * 16;        // 21.0 MB
    short* hA    = (short*)p; p += (size_t)32 * 16384 * 16 + 1024; //  8.4 MB
    short* hB    = (short*)p; p += (size_t)32 * 8192 * 16 + 1024;  //  4.2 MB
    float* c0    = (float*)p; p += (size_t)32768 * 128 * 4;        // 16.8 MB
    float* c1    = (float*)p; p += (size_t)16384 * 128 * 4;        //  8.4 MB
    short* WcatC = (short*)p; p += (size_t)32 * 640 * 16;          // 320 KB
    short* WlfC  = (short*)p; p += (size_t)40 * 256 * 16;          // 160 KB

    reorder_kernel<<<960, 256, 0, stream>>>(W_l, W_r, W_leaf, WcatC, WlfC);
    convx_kernel<<<512, 256, 0, stream>>>(x, xbf);
    leaf_kernel<<<dim3(256, 2), 256, 0, stream>>>(xbf, WlfC, b_leaf, hA, c0);

    const short* hin = hA; const float* cin = c0;
    int M = 16384;
    for (int lev = 1; lev <= 8; ++lev) {
        short* ho = (lev & 1) ? hB : hA;
        float* co = (lev & 1) ? c1 : c0;
        level_ws_kernel<<<dim3((M + 63) / 64, 8), 256, 0, stream>>>(
            hin, cin, WcatC, b, ho, co, M, nullptr);
        hin = ho; cin = co;
        M >>= 1;
    }
    // levels 9-12 fused (hin = level-8 h [32][64] units, cin = level-8 c [128][128])
    tail_kernel<<<1, 512, 0, stream>>>(hin, cin, WcatC, b, out);
}